// Round 21
// baseline (188.448 us; speedup 1.0000x reference)
//
#include <hip/hip_runtime.h>
#include <hip/hip_bf16.h>
#include <math.h>

#define Bsz 16
#define Ntok 785
#define Cdim 768
#define Hn 12
#define HD 64
#define Ttok 797   // Ntok + Hn
#define Kdim 768
#define K3C 2304   // 3*Cdim
#define LN_EPS 1e-5f
#define Mrows (Bsz * Ttok)            // 12752
#define NQS 3                          // max q sub-tiles (64 rows) per flash block
#define NPARTS 5

typedef _Float16 f16;
typedef __attribute__((ext_vector_type(8))) _Float16 half8;
typedef __attribute__((ext_vector_type(4))) _Float16 half4v;
typedef __attribute__((ext_vector_type(8))) unsigned short ushort8;
typedef __attribute__((ext_vector_type(4))) float f32x4;

__device__ inline float wave_sum(float v) {
    #pragma unroll
    for (int off = 32; off; off >>= 1) v += __shfl_xor(v, off, 64);
    return v;
}

// swizzle slot (in f16 units, 8-f16 = 16B granules) for 64-f16 rows
#define SW(row) (((((row) & 7) ^ (((row) >> 3) & 7))) << 3)

// ------- fused: column-sum partials over tokens + x -> fp16 xa rows --------
__global__ void prep_x(const float* __restrict__ x, f16* __restrict__ xa,
                       float* __restrict__ partial) {
    int b = blockIdx.x, ch = blockIdx.y, t = threadIdx.x;
    int n0 = ch * 50, n1 = min(Ntok, n0 + 50);
    float s0 = 0.f, s1 = 0.f, s2 = 0.f;
    for (int n = n0; n < n1; ++n) {
        const float* row = x + ((size_t)b * Ntok + n) * Cdim;
        f16* orow = xa + ((size_t)b * Ttok + n) * Cdim;
        float v0 = row[t], v1 = row[t + 256], v2 = row[t + 512];
        s0 += v0; s1 += v1; s2 += v2;
        orow[t] = (f16)v0; orow[t + 256] = (f16)v1; orow[t + 512] = (f16)v2;
    }
    float* p = partial + ((size_t)b * 16 + ch) * Cdim;
    p[t] = s0; p[t + 256] = s1; p[t + 512] = s2;
}

// ------------- head tokens (fused colmean reduce): -> xa rows [N..T) -------
__global__ void headtok_kernel(const float* __restrict__ partial, const float* __restrict__ htp_w,
                               const float* __restrict__ htp_b, const float* __restrict__ ln_g,
                               const float* __restrict__ ln_b, const float* __restrict__ pos,
                               f16* __restrict__ xa) {
    int blk = blockIdx.x;
    int b  = blk / (Hn * Hn);
    int rem = blk % (Hn * Hn);
    int h  = rem / Hn;
    int h2 = rem % Hn;
    int lane = threadIdx.x;
    int c = h2 * HD + lane;

    float sx = 0.f;
    #pragma unroll
    for (int ch = 0; ch < 16; ++ch)
        sx += partial[((size_t)b * 16 + ch) * Cdim + h * HD + lane];
    float xv = sx * (1.0f / (float)Ntok);

    float acc = htp_b[c];
    #pragma unroll 8
    for (int d = 0; d < HD; ++d) acc += __shfl(xv, d, 64) * htp_w[(size_t)d * Cdim + c];

    float mu = wave_sum(acc) * (1.0f / 64.0f);
    float diff = acc - mu;
    float var = wave_sum(diff * diff) * (1.0f / 64.0f);
    float y = diff * rsqrtf(var + LN_EPS) * ln_g[lane] + ln_b[lane];
    float g = 0.5f * y * (1.0f + erff(y * 0.70710678118654752f));
    float v = g + pos[(size_t)h * Cdim + c];
    xa[((size_t)b * Ttok + Ntok + h) * Cdim + c] = (f16)v;
}

// ------ both weights: W[K][N] -> W^T fp16 [N][K] (LDS tile transpose) ------
__global__ void convert_both(const float* __restrict__ Wq, f16* __restrict__ WTq,
                             const float* __restrict__ Wp, f16* __restrict__ WTp) {
    __shared__ float tile[32][33];
    int bx = blockIdx.x;
    const float* W; f16* WT; int N, nt;
    if (bx < K3C / 32) { W = Wq; WT = WTq; N = K3C; nt = bx * 32; }
    else               { W = Wp; WT = WTp; N = Cdim; nt = (bx - K3C / 32) * 32; }
    int kt = blockIdx.y * 32;
    int tx = threadIdx.x & 31, ty = threadIdx.x >> 5;
    #pragma unroll
    for (int r = 0; r < 32; r += 8)
        tile[ty + r][tx] = W[(size_t)(kt + ty + r) * N + nt + tx];
    __syncthreads();
    #pragma unroll
    for (int r = 0; r < 32; r += 8) {
        int n = nt + ty + r, k = kt + tx;
        WT[(size_t)n * Kdim + k] = (f16)tile[tx][ty + r];
    }
}

// ==================== MFMA fp16 GEMM (dbuf, XCD-partitioned) ===============
// r21: reverted to r19 config (best measured): 128x128 tile, 64x64 wave,
// 2-buffer 32KB, launch_bounds(256,4). Tile-size lever exhausted: 128x256
// (r20) collapsed occupancy to 1 blk/CU -> MfmaUtil 6%; k-grouped (r16) 2x
// staging transactions; all 64x64 scheduling variants ~75us.
__global__ __launch_bounds__(256, 4)
void mfma_gemm(const f16* __restrict__ A, const f16* __restrict__ W,
               const float* __restrict__ bias, int M, int Nn, int mode, int nNb,
               float* __restrict__ outF, float* __restrict__ sbuf,
               f16* __restrict__ outH) {
    __shared__ __align__(16) f16 smem[2][2][4096];
    const int idx = blockIdx.x;
    const int xcd = idx & 7;
    const int sidx = idx >> 3;
    const int mloc = sidx % 13;
    const int nb = sidx / 13;
    const int cnt = (xcd < 4) ? 13 : 12;
    if (mloc >= cnt) return;
    const int mb = (xcd < 4 ? xcd * 13 : 52 + (xcd - 4) * 12) + mloc;
    const int mBase = mb * 128, nBase = nb * 128;

    const int tid = threadIdx.x;
    const int w = tid >> 6, lane = tid & 63;
    const int lr = lane & 15, lg = lane >> 4;
    const int wr = w >> 1, wc = w & 1;

    const f16* src = (w < 2) ? A : W;
    const int arr = w >> 1;
    const int rowOff = (w & 1) * 64;
    const int rowBase = (w < 2) ? mBase : nBase;
    const int rowMax  = (w < 2) ? (M - 1) : (Nn - 1);
    const int cg = (lane & 3) ^ ((lane >> 3) & 3);   // inverse chunk swizzle
    const int sl8 = (lg ^ ((lr >> 1) & 3)) * 8;      // read-side swizzled slot

    f32x4 acc[4][4];
    #pragma unroll
    for (int mi = 0; mi < 4; ++mi)
        #pragma unroll
        for (int ni = 0; ni < 4; ++ni) {
            acc[mi][ni][0] = 0.f; acc[mi][ni][1] = 0.f;
            acc[mi][ni][2] = 0.f; acc[mi][ni][3] = 0.f;
        }

    auto stage = [&](int buf, int k0) {
        #pragma unroll
        for (int i = 0; i < 4; ++i) {
            int r16 = rowOff + i * 16;
            int grow = min(rowBase + r16 + (lane >> 2), rowMax);
            const f16* g = src + (size_t)grow * Kdim + k0 + cg * 8;
            f16* l = &smem[buf][arr][r16 * 32];
            __builtin_amdgcn_global_load_lds(
                (const __attribute__((address_space(1))) void*)g,
                (__attribute__((address_space(3))) void*)l, 16, 0, 0);
        }
    };

    const int NT = Kdim / 32;  // 24
    stage(0, 0);
    stage(1, 32);
    asm volatile("s_waitcnt vmcnt(4)" ::: "memory");
    __builtin_amdgcn_sched_barrier(0);
    __builtin_amdgcn_s_barrier();
    __builtin_amdgcn_sched_barrier(0);

    for (int t = 0; t < NT; ++t) {
        const f16* AS = &smem[t & 1][0][0];
        const f16* WS = &smem[t & 1][1][0];
        half8 a[4], b[4];
        #pragma unroll
        for (int mi = 0; mi < 4; ++mi)
            a[mi] = *reinterpret_cast<const half8*>(&AS[(wr * 64 + mi * 16 + lr) * 32 + sl8]);
        #pragma unroll
        for (int ni = 0; ni < 4; ++ni)
            b[ni] = *reinterpret_cast<const half8*>(&WS[(wc * 64 + ni * 16 + lr) * 32 + sl8]);
        #pragma unroll
        for (int mi = 0; mi < 4; ++mi)
            #pragma unroll
            for (int ni = 0; ni < 4; ++ni)
                acc[mi][ni] = __builtin_amdgcn_mfma_f32_16x16x32_f16(a[mi], b[ni], acc[mi][ni], 0, 0, 0);

        if (t + 1 < NT) {
            asm volatile("s_waitcnt vmcnt(0) lgkmcnt(0)" ::: "memory");
            __builtin_amdgcn_sched_barrier(0);
            __builtin_amdgcn_s_barrier();
            __builtin_amdgcn_sched_barrier(0);
            if (t + 2 < NT) stage(t & 1, (t + 2) * 32);
        }
    }

    if (mode == 0) {
        #pragma unroll
        for (int ni = 0; ni < 4; ++ni) {
            int gn = nBase + wc * 64 + ni * 16 + lr;
            float bv = bias ? bias[gn] : 0.f;
            #pragma unroll
            for (int mi = 0; mi < 4; ++mi)
                #pragma unroll
                for (int r = 0; r < 4; ++r) {
                    int gm = mBase + wr * 64 + mi * 16 + lg * 4 + r;
                    if (gm < M) {
                        int bb = gm / Ttok, tt = gm - bb * Ttok;
                        float v = acc[mi][ni][r] + bv;
                        if (tt >= 1 && tt < Ntok)
                            outF[((size_t)bb * Ntok + tt) * Nn + gn] = v;
                        else
                            sbuf[((size_t)bb * 13 + (tt == 0 ? 0 : tt - Ntok + 1)) * Nn + gn] = v;
                    }
                }
        }
    } else {
        __syncthreads();
        f16* Ew = &smem[0][0][0] + (size_t)w * 4096;
        #pragma unroll
        for (int mi = 0; mi < 4; ++mi)
            #pragma unroll
            for (int ni = 0; ni < 4; ++ni)
                #pragma unroll
                for (int r = 0; r < 4; ++r) {
                    int er = mi * 16 + lg * 4 + r;
                    int ec = ni * 16 + lr;
                    int chunk = ec >> 3;
                    Ew[er * 64 + ((chunk ^ (er & 7)) << 3) + (ec & 7)] = (f16)acc[mi][ni][r];
                }
        __syncthreads();
        int scol = nBase + wc * 64;
        int s = scol / Cdim;
        int hc = scol - s * Cdim;
        int h = hc >> 6;
        #pragma unroll
        for (int c8 = 0; c8 < 8; ++c8) {
            int er = (lane >> 3) + c8 * 8;
            int chunk = lane & 7;
            half8 v = *reinterpret_cast<const half8*>(&Ew[er * 64 + ((chunk ^ (er & 7)) << 3)]);
            int gm = mBase + wr * 64 + er;
            if (gm < M) {
                int bb = gm / Ttok, tt = gm - bb * Ttok;
                f16* dst = outH + (((size_t)(s * Bsz + bb) * Hn + h) * Ttok + tt) * HD + chunk * 8;
                *reinterpret_cast<half8*>(dst) = v;
            }
        }
    }
}

// ==================== MFMA fp16 flash attention (async dbuf, XCD-pinned) ===
// r21: + T5 s_setprio(1) around MFMA clusters (guide m191: +4-7% on attn
// with wave role-split; our async-staging vs compute split qualifies).
__global__ __launch_bounds__(256, 2)
void flash_attn_kernel(const f16* __restrict__ Qb, const f16* __restrict__ Kb,
                       const f16* __restrict__ Vb, f16* __restrict__ ao) {
    __shared__ __align__(16) unsigned short KS[2][64 * 64];
    __shared__ __align__(16) unsigned short VS[2][64 * 64];

    int bh   = blockIdx.x % (Bsz * Hn);
    int part = blockIdx.x / (Bsz * Hn);
    int st   = 3 * part - (part == 4 ? 1 : 0);   // 0,3,6,9,11
    int q0   = st * 64;
    int smax = (part < 3) ? 3 : 2;
    int tid = threadIdx.x;
    int w = tid >> 6, lane = tid & 63;
    int lr = lane & 15, lg = lane >> 4;
    size_t base = (size_t)bh * Ttok * HD;

    half8 qf[NQS][2];
    #pragma unroll
    for (int s = 0; s < NQS; ++s) {
        int qrow = q0 + s * 64 + w * 16 + lr;
        int crow = min(qrow, Ttok - 1);
        #pragma unroll
        for (int kf = 0; kf < 2; ++kf)
            qf[s][kf] = *reinterpret_cast<const half8*>(Qb + base + (size_t)crow * HD + kf * 32 + lg * 8);
    }

    f32x4 O[NQS][4];
    float lsum[NQS];
    #pragma unroll
    for (int s = 0; s < NQS; ++s) {
        lsum[s] = 0.f;
        #pragma unroll
        for (int nt = 0; nt < 4; ++nt) { O[s][nt][0]=0.f; O[s][nt][1]=0.f; O[s][nt][2]=0.f; O[s][nt][3]=0.f; }
    }

    const unsigned short* Kg = (const unsigned short*)(Kb + base);
    const unsigned short* Vg = (const unsigned short*)(Vb + base);

    int pr = tid >> 3;          // key pair 0..31
    int g  = tid & 7;           // dim group (8 dims)
    int k0 = 2 * pr, k1 = k0 + 1;

    ushort8 kv0, kv1, vv0, vv1;
    auto load_tile = [&](int kt) {
        int gk0 = kt * 64 + k0;
        if (kt < 12) {
            kv0 = *reinterpret_cast<const ushort8*>(&Kg[(size_t)gk0 * HD + g * 8]);
            vv0 = *reinterpret_cast<const ushort8*>(&Vg[(size_t)gk0 * HD + g * 8]);
            kv1 = *reinterpret_cast<const ushort8*>(&Kg[(size_t)(gk0 + 1) * HD + g * 8]);
            vv1 = *reinterpret_cast<const ushort8*>(&Vg[(size_t)(gk0 + 1) * HD + g * 8]);
        } else {
            ushort8 z;
            #pragma unroll
            for (int jj = 0; jj < 8; ++jj) z[jj] = 0;
            kv0 = z; vv0 = z; kv1 = z; vv1 = z;
            if (gk0 < Ttok) {
                kv0 = *reinterpret_cast<const ushort8*>(&Kg[(size_t)gk0 * HD + g * 8]);
                vv0 = *reinterpret_cast<const ushort8*>(&Vg[(size_t)gk0 * HD + g * 8]);
            }
            if (gk0 + 1 < Ttok) {
                kv1 = *reinterpret_cast<const ushort8*>(&Kg[(size_t)(gk0 + 1) * HD + g * 8]);
                vv1 = *reinterpret_cast<const ushort8*>(&Vg[(size_t)(gk0 + 1) * HD + g * 8]);
            }
        }
    };
    auto write_tile = [&](int buf) {
        *reinterpret_cast<ushort8*>(&KS[buf][(k0 * 64 + g * 8) ^ SW(k0)]) = kv0;
        *reinterpret_cast<ushort8*>(&KS[buf][(k1 * 64 + g * 8) ^ SW(k1)]) = kv1;
        unsigned* VTd = reinterpret_cast<unsigned*>(&VS[buf][0]);
        #pragma unroll
        for (int jj = 0; jj < 8; ++jj) {
            int dim = g * 8 + jj;
            unsigned w2 = (unsigned)vv0[jj] | ((unsigned)vv1[jj] << 16);
            VTd[dim * 32 + (pr ^ ((((dim & 7) ^ ((dim >> 3) & 7))) << 2))] = w2;
        }
    };

    load_tile(0);
    write_tile(0);
    load_tile(1);
    asm volatile("s_waitcnt lgkmcnt(0)" ::: "memory");
    __builtin_amdgcn_sched_barrier(0);
    __builtin_amdgcn_s_barrier();
    __builtin_amdgcn_sched_barrier(0);

    for (int kt = 0; kt < 13; ++kt) {
        bool tail = (kt == 12);
        int cur = kt & 1;
        const unsigned short* KSc = &KS[cur][0];
        const unsigned short* VSc = &VS[cur][0];

        int kbase = kt * 64;
        #pragma unroll
        for (int s = 0; s < NQS; ++s) {
            if (s < smax) {
                half4v pa[4];
                float ls = 0.f;
                __builtin_amdgcn_s_setprio(1);
                #pragma unroll
                for (int ntk = 0; ntk < 4; ++ntk) {
                    f32x4 sc; sc[0]=0.f; sc[1]=0.f; sc[2]=0.f; sc[3]=0.f;
                    #pragma unroll
                    for (int kf = 0; kf < 2; ++kf) {
                        int key = ntk * 16 + lr;
                        int d0 = kf * 32 + lg * 8;
                        half8 k8 = *reinterpret_cast<const half8*>(
                            reinterpret_cast<const f16*>(&KSc[(key * 64 + d0) ^ SW(key)]));
                        sc = __builtin_amdgcn_mfma_f32_16x16x32_f16(k8, qf[s][kf], sc, 0, 0, 0);
                    }
                    float p[4];
                    if (!tail) {
                        #pragma unroll
                        for (int r = 0; r < 4; ++r) {
                            p[r] = __expf(sc[r] * 0.125f - 6.0f);
                            ls += p[r];
                        }
                    } else {
                        int kb2 = kbase + ntk * 16 + lg * 4;
                        #pragma unroll
                        for (int r = 0; r < 4; ++r) {
                            bool valid = (kb2 + r) < Ttok;
                            p[r] = valid ? __expf(sc[r] * 0.125f - 6.0f) : 0.f;
                            ls += p[r];
                        }
                    }
                    auto lo = __builtin_amdgcn_cvt_pkrtz(p[0], p[1]);
                    auto hi = __builtin_amdgcn_cvt_pkrtz(p[2], p[3]);
                    pa[ntk][0] = (f16)lo[0]; pa[ntk][1] = (f16)lo[1];
                    pa[ntk][2] = (f16)hi[0]; pa[ntk][3] = (f16)hi[1];
                }
                lsum[s] += ls;
                #pragma unroll
                for (int ntd = 0; ntd < 4; ++ntd) {
                    int dim = ntd * 16 + lr;
                    #pragma unroll
                    for (int ntk = 0; ntk < 4; ++ntk) {
                        half4v v4 = *reinterpret_cast<const half4v*>(
                            reinterpret_cast<const f16*>(&VSc[(dim * 64 + ntk * 16 + lg * 4) ^ SW(dim)]));
                        O[s][ntd] = __builtin_amdgcn_mfma_f32_16x16x16f16(pa[ntk], v4, O[s][ntd], 0, 0, 0);
                    }
                }
                __builtin_amdgcn_s_setprio(0);
            }
        }

        if (kt + 1 < 13) {
            write_tile((kt + 1) & 1);
            if (kt + 2 < 13) load_tile(kt + 2);
            asm volatile("s_waitcnt lgkmcnt(0)" ::: "memory");
            __builtin_amdgcn_sched_barrier(0);
            __builtin_amdgcn_s_barrier();
            __builtin_amdgcn_sched_barrier(0);
        }
    }

    __syncthreads();
    int b = bh / Hn, h = bh % Hn;
    f16* Ew = reinterpret_cast<f16*>(&KS[0][(size_t)w * 1024]);
    #pragma unroll
    for (int s = 0; s < NQS; ++s) {
        if (s < smax) {
            float l = lsum[s];
            l += __shfl_xor(l, 16, 64);
            l += __shfl_xor(l, 32, 64);
            float inv[4];
            #pragma unroll
            for (int r = 0; r < 4; ++r)
                inv[r] = 1.0f / __shfl(l, lg * 4 + r, 64);
            #pragma unroll
            for (int nt = 0; nt < 4; ++nt)
                #pragma unroll
                for (int r = 0; r < 4; ++r)
                    Ew[(lg * 4 + r) * 64 + nt * 16 + lr] = (f16)(O[s][nt][r] * inv[r]);
            int row = lane >> 2, seg = lane & 3;
            half8 v0 = *reinterpret_cast<const half8*>(&Ew[row * 64 + seg * 16]);
            half8 v1 = *reinterpret_cast<const half8*>(&Ew[row * 64 + seg * 16 + 8]);
            int qrow = q0 + s * 64 + w * 16 + row;
            if (qrow < Ttok) {
                f16* dst = ao + ((size_t)b * Ttok + qrow) * Cdim + h * HD + seg * 16;
                *reinterpret_cast<half8*>(dst) = v0;
                *reinterpret_cast<half8*>(dst + 8) = v1;
            }
        }
    }
}

// -------------------- cls row from side buffer -----------------------------
__global__ void cls2_kernel(const float* __restrict__ sbuf, float* __restrict__ out) {
    int b = blockIdx.x, t = threadIdx.x;
    #pragma unroll
    for (int i = 0; i < 3; ++i) {
        int c = t + i * 256;
        float s = sbuf[((size_t)b * 13) * Cdim + c];
        float hs = 0.f;
        #pragma unroll
        for (int h = 0; h < Hn; ++h)
            hs += sbuf[((size_t)b * 13 + 1 + h) * Cdim + c];
        out[((size_t)b * Ntok) * Cdim + c] = s + hs * (1.0f / (float)Hn);
    }
}

extern "C" void kernel_launch(void* const* d_in, const int* in_sizes, int n_in,
                              void* d_out, int out_size, void* d_ws, size_t ws_size,
                              hipStream_t stream) {
    const float* x      = (const float*)d_in[0];
    const float* qkv_w  = (const float*)d_in[1];
    const float* proj_w = (const float*)d_in[2];
    const float* proj_b = (const float*)d_in[3];
    const float* htp_w  = (const float*)d_in[4];
    const float* htp_b  = (const float*)d_in[5];
    const float* ln_g   = (const float*)d_in[6];
    const float* ln_b   = (const float*)d_in[7];
    const float* pos    = (const float*)d_in[8];
    float* out = (float*)d_out;

    const size_t MC = (size_t)Mrows * Cdim;        // 9,793,536
    const size_t WQ = (size_t)K3C * Kdim;          // 1,769,472
    const size_t WP = (size_t)Cdim * Kdim;         // 589,824

    f16* qkv   = (f16*)d_ws;                       // 3*MC f16 (Q,K,V)
    f16* xa    = qkv + 3 * MC;                     // MC f16 (input; later attnout)
    f16* wq    = xa + MC;                          // WQ f16  (qkv_w^T)
    f16* wp    = wq + WQ;                          // WP f16  (proj_w^T)
    float* partial = (float*)(wp + WP);            // B*16*C fp32
    float* sbuf    = partial + (size_t)Bsz * 16 * Cdim;  // B*13*C fp32

    prep_x<<<dim3(Bsz, 16), 256, 0, stream>>>(x, xa, partial);
    headtok_kernel<<<Bsz * Hn * Hn, 64, 0, stream>>>(partial, htp_w, htp_b, ln_g, ln_b, pos, xa);
    convert_both<<<dim3(96, Kdim / 32), 256, 0, stream>>>(qkv_w, wq, proj_w, wp);

    mfma_gemm<<<8 * 13 * 18, 256, 0, stream>>>(
        xa, wq, nullptr, Mrows, K3C, 1, 18, nullptr, nullptr, qkv);

    flash_attn_kernel<<<Bsz * Hn * NPARTS, 256, 0, stream>>>(
        qkv, qkv + MC, qkv + 2 * MC, xa);

    mfma_gemm<<<8 * 13 * 6, 256, 0, stream>>>(
        xa, wp, proj_b, Mrows, Cdim, 0, 6, out, sbuf, nullptr);

    cls2_kernel<<<Bsz, 256, 0, stream>>>(sbuf, out);
}

// Round 22
// 185.726 us; speedup vs baseline: 1.0147x; 1.0147x over previous
//
#include <hip/hip_runtime.h>
#include <hip/hip_bf16.h>
#include <math.h>

#define Bsz 16
#define Ntok 785
#define Cdim 768
#define Hn 12
#define HD 64
#define Ttok 797   // Ntok + Hn
#define Kdim 768
#define K3C 2304   // 3*Cdim
#define LN_EPS 1e-5f
#define Mrows (Bsz * Ttok)            // 12752
#define NQS 3                          // max q sub-tiles (64 rows) per flash block
#define NPARTS 5

typedef _Float16 f16;
typedef __attribute__((ext_vector_type(8))) _Float16 half8;
typedef __attribute__((ext_vector_type(4))) _Float16 half4v;
typedef __attribute__((ext_vector_type(8))) unsigned short ushort8;
typedef __attribute__((ext_vector_type(4))) float f32x4;

__device__ inline float wave_sum(float v) {
    #pragma unroll
    for (int off = 32; off; off >>= 1) v += __shfl_xor(v, off, 64);
    return v;
}

// swizzle slot (in f16 units, 8-f16 = 16B granules) for 64-f16 rows
#define SW(row) (((((row) & 7) ^ (((row) >> 3) & 7))) << 3)

// ------- fused: column-sum partials over tokens + x -> fp16 xa rows --------
__global__ void prep_x(const float* __restrict__ x, f16* __restrict__ xa,
                       float* __restrict__ partial) {
    int b = blockIdx.x, ch = blockIdx.y, t = threadIdx.x;
    int n0 = ch * 50, n1 = min(Ntok, n0 + 50);
    float s0 = 0.f, s1 = 0.f, s2 = 0.f;
    for (int n = n0; n < n1; ++n) {
        const float* row = x + ((size_t)b * Ntok + n) * Cdim;
        f16* orow = xa + ((size_t)b * Ttok + n) * Cdim;
        float v0 = row[t], v1 = row[t + 256], v2 = row[t + 512];
        s0 += v0; s1 += v1; s2 += v2;
        orow[t] = (f16)v0; orow[t + 256] = (f16)v1; orow[t + 512] = (f16)v2;
    }
    float* p = partial + ((size_t)b * 16 + ch) * Cdim;
    p[t] = s0; p[t + 256] = s1; p[t + 512] = s2;
}

// ------------- head tokens (fused colmean reduce): -> xa rows [N..T) -------
__global__ void headtok_kernel(const float* __restrict__ partial, const float* __restrict__ htp_w,
                               const float* __restrict__ htp_b, const float* __restrict__ ln_g,
                               const float* __restrict__ ln_b, const float* __restrict__ pos,
                               f16* __restrict__ xa) {
    int blk = blockIdx.x;
    int b  = blk / (Hn * Hn);
    int rem = blk % (Hn * Hn);
    int h  = rem / Hn;
    int h2 = rem % Hn;
    int lane = threadIdx.x;
    int c = h2 * HD + lane;

    float sx = 0.f;
    #pragma unroll
    for (int ch = 0; ch < 16; ++ch)
        sx += partial[((size_t)b * 16 + ch) * Cdim + h * HD + lane];
    float xv = sx * (1.0f / (float)Ntok);

    float acc = htp_b[c];
    #pragma unroll 8
    for (int d = 0; d < HD; ++d) acc += __shfl(xv, d, 64) * htp_w[(size_t)d * Cdim + c];

    float mu = wave_sum(acc) * (1.0f / 64.0f);
    float diff = acc - mu;
    float var = wave_sum(diff * diff) * (1.0f / 64.0f);
    float y = diff * rsqrtf(var + LN_EPS) * ln_g[lane] + ln_b[lane];
    float g = 0.5f * y * (1.0f + erff(y * 0.70710678118654752f));
    float v = g + pos[(size_t)h * Cdim + c];
    xa[((size_t)b * Ttok + Ntok + h) * Cdim + c] = (f16)v;
}

// ------ both weights: W[K][N] -> W^T fp16 [N][K] (LDS tile transpose) ------
__global__ void convert_both(const float* __restrict__ Wq, f16* __restrict__ WTq,
                             const float* __restrict__ Wp, f16* __restrict__ WTp) {
    __shared__ float tile[32][33];
    int bx = blockIdx.x;
    const float* W; f16* WT; int N, nt;
    if (bx < K3C / 32) { W = Wq; WT = WTq; N = K3C; nt = bx * 32; }
    else               { W = Wp; WT = WTp; N = Cdim; nt = (bx - K3C / 32) * 32; }
    int kt = blockIdx.y * 32;
    int tx = threadIdx.x & 31, ty = threadIdx.x >> 5;
    #pragma unroll
    for (int r = 0; r < 32; r += 8)
        tile[ty + r][tx] = W[(size_t)(kt + ty + r) * N + nt + tx];
    __syncthreads();
    #pragma unroll
    for (int r = 0; r < 32; r += 8) {
        int n = nt + ty + r, k = kt + tx;
        WT[(size_t)n * Kdim + k] = (f16)tile[tx][ty + r];
    }
}

// ==================== MFMA fp16 GEMM (dbuf, XCD-partitioned) ===============
// Final config (best measured): 128x128 tile, 64x64 wave, 2-buffer 32KB,
// launch_bounds(256,4), XCD M-partition, r17-verified conflict-free swizzle.
__global__ __launch_bounds__(256, 4)
void mfma_gemm(const f16* __restrict__ A, const f16* __restrict__ W,
               const float* __restrict__ bias, int M, int Nn, int mode, int nNb,
               float* __restrict__ outF, float* __restrict__ sbuf,
               f16* __restrict__ outH) {
    __shared__ __align__(16) f16 smem[2][2][4096];
    const int idx = blockIdx.x;
    const int xcd = idx & 7;
    const int sidx = idx >> 3;
    const int mloc = sidx % 13;
    const int nb = sidx / 13;
    const int cnt = (xcd < 4) ? 13 : 12;
    if (mloc >= cnt) return;
    const int mb = (xcd < 4 ? xcd * 13 : 52 + (xcd - 4) * 12) + mloc;
    const int mBase = mb * 128, nBase = nb * 128;

    const int tid = threadIdx.x;
    const int w = tid >> 6, lane = tid & 63;
    const int lr = lane & 15, lg = lane >> 4;
    const int wr = w >> 1, wc = w & 1;

    const f16* src = (w < 2) ? A : W;
    const int arr = w >> 1;
    const int rowOff = (w & 1) * 64;
    const int rowBase = (w < 2) ? mBase : nBase;
    const int rowMax  = (w < 2) ? (M - 1) : (Nn - 1);
    const int cg = (lane & 3) ^ ((lane >> 3) & 3);   // inverse chunk swizzle
    const int sl8 = (lg ^ ((lr >> 1) & 3)) * 8;      // read-side swizzled slot

    f32x4 acc[4][4];
    #pragma unroll
    for (int mi = 0; mi < 4; ++mi)
        #pragma unroll
        for (int ni = 0; ni < 4; ++ni) {
            acc[mi][ni][0] = 0.f; acc[mi][ni][1] = 0.f;
            acc[mi][ni][2] = 0.f; acc[mi][ni][3] = 0.f;
        }

    auto stage = [&](int buf, int k0) {
        #pragma unroll
        for (int i = 0; i < 4; ++i) {
            int r16 = rowOff + i * 16;
            int grow = min(rowBase + r16 + (lane >> 2), rowMax);
            const f16* g = src + (size_t)grow * Kdim + k0 + cg * 8;
            f16* l = &smem[buf][arr][r16 * 32];
            __builtin_amdgcn_global_load_lds(
                (const __attribute__((address_space(1))) void*)g,
                (__attribute__((address_space(3))) void*)l, 16, 0, 0);
        }
    };

    const int NT = Kdim / 32;  // 24
    stage(0, 0);
    stage(1, 32);
    asm volatile("s_waitcnt vmcnt(4)" ::: "memory");
    __builtin_amdgcn_sched_barrier(0);
    __builtin_amdgcn_s_barrier();
    __builtin_amdgcn_sched_barrier(0);

    for (int t = 0; t < NT; ++t) {
        const f16* AS = &smem[t & 1][0][0];
        const f16* WS = &smem[t & 1][1][0];
        half8 a[4], b[4];
        #pragma unroll
        for (int mi = 0; mi < 4; ++mi)
            a[mi] = *reinterpret_cast<const half8*>(&AS[(wr * 64 + mi * 16 + lr) * 32 + sl8]);
        #pragma unroll
        for (int ni = 0; ni < 4; ++ni)
            b[ni] = *reinterpret_cast<const half8*>(&WS[(wc * 64 + ni * 16 + lr) * 32 + sl8]);
        #pragma unroll
        for (int mi = 0; mi < 4; ++mi)
            #pragma unroll
            for (int ni = 0; ni < 4; ++ni)
                acc[mi][ni] = __builtin_amdgcn_mfma_f32_16x16x32_f16(a[mi], b[ni], acc[mi][ni], 0, 0, 0);

        if (t + 1 < NT) {
            asm volatile("s_waitcnt vmcnt(0) lgkmcnt(0)" ::: "memory");
            __builtin_amdgcn_sched_barrier(0);
            __builtin_amdgcn_s_barrier();
            __builtin_amdgcn_sched_barrier(0);
            if (t + 2 < NT) stage(t & 1, (t + 2) * 32);
        }
    }

    if (mode == 0) {
        #pragma unroll
        for (int ni = 0; ni < 4; ++ni) {
            int gn = nBase + wc * 64 + ni * 16 + lr;
            float bv = bias ? bias[gn] : 0.f;
            #pragma unroll
            for (int mi = 0; mi < 4; ++mi)
                #pragma unroll
                for (int r = 0; r < 4; ++r) {
                    int gm = mBase + wr * 64 + mi * 16 + lg * 4 + r;
                    if (gm < M) {
                        int bb = gm / Ttok, tt = gm - bb * Ttok;
                        float v = acc[mi][ni][r] + bv;
                        if (tt >= 1 && tt < Ntok)
                            outF[((size_t)bb * Ntok + tt) * Nn + gn] = v;
                        else
                            sbuf[((size_t)bb * 13 + (tt == 0 ? 0 : tt - Ntok + 1)) * Nn + gn] = v;
                    }
                }
        }
    } else {
        __syncthreads();
        f16* Ew = &smem[0][0][0] + (size_t)w * 4096;
        #pragma unroll
        for (int mi = 0; mi < 4; ++mi)
            #pragma unroll
            for (int ni = 0; ni < 4; ++ni)
                #pragma unroll
                for (int r = 0; r < 4; ++r) {
                    int er = mi * 16 + lg * 4 + r;
                    int ec = ni * 16 + lr;
                    int chunk = ec >> 3;
                    Ew[er * 64 + ((chunk ^ (er & 7)) << 3) + (ec & 7)] = (f16)acc[mi][ni][r];
                }
        __syncthreads();
        int scol = nBase + wc * 64;
        int s = scol / Cdim;
        int hc = scol - s * Cdim;
        int h = hc >> 6;
        #pragma unroll
        for (int c8 = 0; c8 < 8; ++c8) {
            int er = (lane >> 3) + c8 * 8;
            int chunk = lane & 7;
            half8 v = *reinterpret_cast<const half8*>(&Ew[er * 64 + ((chunk ^ (er & 7)) << 3)]);
            int gm = mBase + wr * 64 + er;
            if (gm < M) {
                int bb = gm / Ttok, tt = gm - bb * Ttok;
                f16* dst = outH + (((size_t)(s * Bsz + bb) * Hn + h) * Ttok + tt) * HD + chunk * 8;
                *reinterpret_cast<half8*>(dst) = v;
            }
        }
    }
}

// ==================== MFMA fp16 flash attention (async dbuf, XCD-pinned) ===
__global__ __launch_bounds__(256, 2)
void flash_attn_kernel(const f16* __restrict__ Qb, const f16* __restrict__ Kb,
                       const f16* __restrict__ Vb, f16* __restrict__ ao) {
    __shared__ __align__(16) unsigned short KS[2][64 * 64];
    __shared__ __align__(16) unsigned short VS[2][64 * 64];

    int bh   = blockIdx.x % (Bsz * Hn);
    int part = blockIdx.x / (Bsz * Hn);
    int st   = 3 * part - (part == 4 ? 1 : 0);   // 0,3,6,9,11
    int q0   = st * 64;
    int smax = (part < 3) ? 3 : 2;
    int tid = threadIdx.x;
    int w = tid >> 6, lane = tid & 63;
    int lr = lane & 15, lg = lane >> 4;
    size_t base = (size_t)bh * Ttok * HD;

    half8 qf[NQS][2];
    #pragma unroll
    for (int s = 0; s < NQS; ++s) {
        int qrow = q0 + s * 64 + w * 16 + lr;
        int crow = min(qrow, Ttok - 1);
        #pragma unroll
        for (int kf = 0; kf < 2; ++kf)
            qf[s][kf] = *reinterpret_cast<const half8*>(Qb + base + (size_t)crow * HD + kf * 32 + lg * 8);
    }

    f32x4 O[NQS][4];
    float lsum[NQS];
    #pragma unroll
    for (int s = 0; s < NQS; ++s) {
        lsum[s] = 0.f;
        #pragma unroll
        for (int nt = 0; nt < 4; ++nt) { O[s][nt][0]=0.f; O[s][nt][1]=0.f; O[s][nt][2]=0.f; O[s][nt][3]=0.f; }
    }

    const unsigned short* Kg = (const unsigned short*)(Kb + base);
    const unsigned short* Vg = (const unsigned short*)(Vb + base);

    int pr = tid >> 3;          // key pair 0..31
    int g  = tid & 7;           // dim group (8 dims)
    int k0 = 2 * pr, k1 = k0 + 1;

    ushort8 kv0, kv1, vv0, vv1;
    auto load_tile = [&](int kt) {
        int gk0 = kt * 64 + k0;
        if (kt < 12) {
            kv0 = *reinterpret_cast<const ushort8*>(&Kg[(size_t)gk0 * HD + g * 8]);
            vv0 = *reinterpret_cast<const ushort8*>(&Vg[(size_t)gk0 * HD + g * 8]);
            kv1 = *reinterpret_cast<const ushort8*>(&Kg[(size_t)(gk0 + 1) * HD + g * 8]);
            vv1 = *reinterpret_cast<const ushort8*>(&Vg[(size_t)(gk0 + 1) * HD + g * 8]);
        } else {
            ushort8 z;
            #pragma unroll
            for (int jj = 0; jj < 8; ++jj) z[jj] = 0;
            kv0 = z; vv0 = z; kv1 = z; vv1 = z;
            if (gk0 < Ttok) {
                kv0 = *reinterpret_cast<const ushort8*>(&Kg[(size_t)gk0 * HD + g * 8]);
                vv0 = *reinterpret_cast<const ushort8*>(&Vg[(size_t)gk0 * HD + g * 8]);
            }
            if (gk0 + 1 < Ttok) {
                kv1 = *reinterpret_cast<const ushort8*>(&Kg[(size_t)(gk0 + 1) * HD + g * 8]);
                vv1 = *reinterpret_cast<const ushort8*>(&Vg[(size_t)(gk0 + 1) * HD + g * 8]);
            }
        }
    };
    auto write_tile = [&](int buf) {
        *reinterpret_cast<ushort8*>(&KS[buf][(k0 * 64 + g * 8) ^ SW(k0)]) = kv0;
        *reinterpret_cast<ushort8*>(&KS[buf][(k1 * 64 + g * 8) ^ SW(k1)]) = kv1;
        unsigned* VTd = reinterpret_cast<unsigned*>(&VS[buf][0]);
        #pragma unroll
        for (int jj = 0; jj < 8; ++jj) {
            int dim = g * 8 + jj;
            unsigned w2 = (unsigned)vv0[jj] | ((unsigned)vv1[jj] << 16);
            VTd[dim * 32 + (pr ^ ((((dim & 7) ^ ((dim >> 3) & 7))) << 2))] = w2;
        }
    };

    load_tile(0);
    write_tile(0);
    load_tile(1);
    asm volatile("s_waitcnt lgkmcnt(0)" ::: "memory");
    __builtin_amdgcn_sched_barrier(0);
    __builtin_amdgcn_s_barrier();
    __builtin_amdgcn_sched_barrier(0);

    for (int kt = 0; kt < 13; ++kt) {
        bool tail = (kt == 12);
        int cur = kt & 1;
        const unsigned short* KSc = &KS[cur][0];
        const unsigned short* VSc = &VS[cur][0];

        int kbase = kt * 64;
        #pragma unroll
        for (int s = 0; s < NQS; ++s) {
            if (s < smax) {
                half4v pa[4];
                float ls = 0.f;
                #pragma unroll
                for (int ntk = 0; ntk < 4; ++ntk) {
                    f32x4 sc; sc[0]=0.f; sc[1]=0.f; sc[2]=0.f; sc[3]=0.f;
                    #pragma unroll
                    for (int kf = 0; kf < 2; ++kf) {
                        int key = ntk * 16 + lr;
                        int d0 = kf * 32 + lg * 8;
                        half8 k8 = *reinterpret_cast<const half8*>(
                            reinterpret_cast<const f16*>(&KSc[(key * 64 + d0) ^ SW(key)]));
                        sc = __builtin_amdgcn_mfma_f32_16x16x32_f16(k8, qf[s][kf], sc, 0, 0, 0);
                    }
                    float p[4];
                    if (!tail) {
                        #pragma unroll
                        for (int r = 0; r < 4; ++r) {
                            p[r] = __expf(sc[r] * 0.125f - 6.0f);
                            ls += p[r];
                        }
                    } else {
                        int kb2 = kbase + ntk * 16 + lg * 4;
                        #pragma unroll
                        for (int r = 0; r < 4; ++r) {
                            bool valid = (kb2 + r) < Ttok;
                            p[r] = valid ? __expf(sc[r] * 0.125f - 6.0f) : 0.f;
                            ls += p[r];
                        }
                    }
                    auto lo = __builtin_amdgcn_cvt_pkrtz(p[0], p[1]);
                    auto hi = __builtin_amdgcn_cvt_pkrtz(p[2], p[3]);
                    pa[ntk][0] = (f16)lo[0]; pa[ntk][1] = (f16)lo[1];
                    pa[ntk][2] = (f16)hi[0]; pa[ntk][3] = (f16)hi[1];
                }
                lsum[s] += ls;
                #pragma unroll
                for (int ntd = 0; ntd < 4; ++ntd) {
                    int dim = ntd * 16 + lr;
                    #pragma unroll
                    for (int ntk = 0; ntk < 4; ++ntk) {
                        half4v v4 = *reinterpret_cast<const half4v*>(
                            reinterpret_cast<const f16*>(&VSc[(dim * 64 + ntk * 16 + lg * 4) ^ SW(dim)]));
                        O[s][ntd] = __builtin_amdgcn_mfma_f32_16x16x16f16(pa[ntk], v4, O[s][ntd], 0, 0, 0);
                    }
                }
            }
        }

        if (kt + 1 < 13) {
            write_tile((kt + 1) & 1);
            if (kt + 2 < 13) load_tile(kt + 2);
            asm volatile("s_waitcnt lgkmcnt(0)" ::: "memory");
            __builtin_amdgcn_sched_barrier(0);
            __builtin_amdgcn_s_barrier();
            __builtin_amdgcn_sched_barrier(0);
        }
    }

    __syncthreads();
    int b = bh / Hn, h = bh % Hn;
    f16* Ew = reinterpret_cast<f16*>(&KS[0][(size_t)w * 1024]);
    #pragma unroll
    for (int s = 0; s < NQS; ++s) {
        if (s < smax) {
            float l = lsum[s];
            l += __shfl_xor(l, 16, 64);
            l += __shfl_xor(l, 32, 64);
            float inv[4];
            #pragma unroll
            for (int r = 0; r < 4; ++r)
                inv[r] = 1.0f / __shfl(l, lg * 4 + r, 64);
            #pragma unroll
            for (int nt = 0; nt < 4; ++nt)
                #pragma unroll
                for (int r = 0; r < 4; ++r)
                    Ew[(lg * 4 + r) * 64 + nt * 16 + lr] = (f16)(O[s][nt][r] * inv[r]);
            int row = lane >> 2, seg = lane & 3;
            half8 v0 = *reinterpret_cast<const half8*>(&Ew[row * 64 + seg * 16]);
            half8 v1 = *reinterpret_cast<const half8*>(&Ew[row * 64 + seg * 16 + 8]);
            int qrow = q0 + s * 64 + w * 16 + row;
            if (qrow < Ttok) {
                f16* dst = ao + ((size_t)b * Ttok + qrow) * Cdim + h * HD + seg * 16;
                *reinterpret_cast<half8*>(dst) = v0;
                *reinterpret_cast<half8*>(dst + 8) = v1;
            }
        }
    }
}

// -------------------- cls row from side buffer -----------------------------
__global__ void cls2_kernel(const float* __restrict__ sbuf, float* __restrict__ out) {
    int b = blockIdx.x, t = threadIdx.x;
    #pragma unroll
    for (int i = 0; i < 3; ++i) {
        int c = t + i * 256;
        float s = sbuf[((size_t)b * 13) * Cdim + c];
        float hs = 0.f;
        #pragma unroll
        for (int h = 0; h < Hn; ++h)
            hs += sbuf[((size_t)b * 13 + 1 + h) * Cdim + c];
        out[((size_t)b * Ntok) * Cdim + c] = s + hs * (1.0f / (float)Hn);
    }
}

extern "C" void kernel_launch(void* const* d_in, const int* in_sizes, int n_in,
                              void* d_out, int out_size, void* d_ws, size_t ws_size,
                              hipStream_t stream) {
    const float* x      = (const float*)d_in[0];
    const float* qkv_w  = (const float*)d_in[1];
    const float* proj_w = (const float*)d_in[2];
    const float* proj_b = (const float*)d_in[3];
    const float* htp_w  = (const float*)d_in[4];
    const float* htp_b  = (const float*)d_in[5];
    const float* ln_g   = (const float*)d_in[6];
    const float* ln_b   = (const float*)d_in[7];
    const float* pos    = (const float*)d_in[8];
    float* out = (float*)d_out;

    const size_t MC = (size_t)Mrows * Cdim;        // 9,793,536
    const size_t WQ = (size_t)K3C * Kdim;          // 1,769,472
    const size_t WP = (size_t)Cdim * Kdim;         // 589,824

    f16* qkv   = (f16*)d_ws;                       // 3*MC f16 (Q,K,V)
    f16* xa    = qkv + 3 * MC;                     // MC f16 (input; later attnout)
    f16* wq    = xa + MC;                          // WQ f16  (qkv_w^T)
    f16* wp    = wq + WQ;                          // WP f16  (proj_w^T)
    float* partial = (float*)(wp + WP);            // B*16*C fp32
    float* sbuf    = partial + (size_t)Bsz * 16 * Cdim;  // B*13*C fp32

    prep_x<<<dim3(Bsz, 16), 256, 0, stream>>>(x, xa, partial);
    headtok_kernel<<<Bsz * Hn * Hn, 64, 0, stream>>>(partial, htp_w, htp_b, ln_g, ln_b, pos, xa);
    convert_both<<<dim3(96, Kdim / 32), 256, 0, stream>>>(qkv_w, wq, proj_w, wp);

    mfma_gemm<<<8 * 13 * 18, 256, 0, stream>>>(
        xa, wq, nullptr, Mrows, K3C, 1, 18, nullptr, nullptr, qkv);

    flash_attn_kernel<<<Bsz * Hn * NPARTS, 256, 0, stream>>>(
        qkv, qkv + MC, qkv + 2 * MC, xa);

    mfma_gemm<<<8 * 13 * 6, 256, 0, stream>>>(
        xa, wp, proj_b, Mrows, Cdim, 0, 6, out, sbuf, nullptr);

    cls2_kernel<<<Bsz, 256, 0, stream>>>(sbuf, out);
}

// Round 23
// 185.520 us; speedup vs baseline: 1.0158x; 1.0011x over previous
//
#include <hip/hip_runtime.h>
#include <hip/hip_bf16.h>
#include <math.h>

#define Bsz 16
#define Ntok 785
#define Cdim 768
#define Hn 12
#define HD 64
#define Ttok 797   // Ntok + Hn
#define Kdim 768
#define K3C 2304   // 3*Cdim
#define LN_EPS 1e-5f
#define Mrows (Bsz * Ttok)            // 12752
#define NQS 3                          // max q sub-tiles (64 rows) per flash block
#define NPARTS 5

typedef _Float16 f16;
typedef __attribute__((ext_vector_type(8))) _Float16 half8;
typedef __attribute__((ext_vector_type(4))) _Float16 half4v;
typedef __attribute__((ext_vector_type(8))) unsigned short ushort8;
typedef __attribute__((ext_vector_type(4))) float f32x4;

__device__ inline float wave_sum(float v) {
    #pragma unroll
    for (int off = 32; off; off >>= 1) v += __shfl_xor(v, off, 64);
    return v;
}

// swizzle slot (in f16 units, 8-f16 = 16B granules) for 64-f16 rows
#define SW(row) (((((row) & 7) ^ (((row) >> 3) & 7))) << 3)

// ------- fused: column-sum partials over tokens + x -> fp16 xa rows --------
__global__ void prep_x(const float* __restrict__ x, f16* __restrict__ xa,
                       float* __restrict__ partial) {
    int b = blockIdx.x, ch = blockIdx.y, t = threadIdx.x;
    int n0 = ch * 50, n1 = min(Ntok, n0 + 50);
    float s0 = 0.f, s1 = 0.f, s2 = 0.f;
    for (int n = n0; n < n1; ++n) {
        const float* row = x + ((size_t)b * Ntok + n) * Cdim;
        f16* orow = xa + ((size_t)b * Ttok + n) * Cdim;
        float v0 = row[t], v1 = row[t + 256], v2 = row[t + 512];
        s0 += v0; s1 += v1; s2 += v2;
        orow[t] = (f16)v0; orow[t + 256] = (f16)v1; orow[t + 512] = (f16)v2;
    }
    float* p = partial + ((size_t)b * 16 + ch) * Cdim;
    p[t] = s0; p[t + 256] = s1; p[t + 512] = s2;
}

// ------------- head tokens (fused colmean reduce): -> xa rows [N..T) -------
__global__ void headtok_kernel(const float* __restrict__ partial, const float* __restrict__ htp_w,
                               const float* __restrict__ htp_b, const float* __restrict__ ln_g,
                               const float* __restrict__ ln_b, const float* __restrict__ pos,
                               f16* __restrict__ xa) {
    int blk = blockIdx.x;
    int b  = blk / (Hn * Hn);
    int rem = blk % (Hn * Hn);
    int h  = rem / Hn;
    int h2 = rem % Hn;
    int lane = threadIdx.x;
    int c = h2 * HD + lane;

    float sx = 0.f;
    #pragma unroll
    for (int ch = 0; ch < 16; ++ch)
        sx += partial[((size_t)b * 16 + ch) * Cdim + h * HD + lane];
    float xv = sx * (1.0f / (float)Ntok);

    float acc = htp_b[c];
    #pragma unroll 8
    for (int d = 0; d < HD; ++d) acc += __shfl(xv, d, 64) * htp_w[(size_t)d * Cdim + c];

    float mu = wave_sum(acc) * (1.0f / 64.0f);
    float diff = acc - mu;
    float var = wave_sum(diff * diff) * (1.0f / 64.0f);
    float y = diff * rsqrtf(var + LN_EPS) * ln_g[lane] + ln_b[lane];
    float g = 0.5f * y * (1.0f + erff(y * 0.70710678118654752f));
    float v = g + pos[(size_t)h * Cdim + c];
    xa[((size_t)b * Ttok + Ntok + h) * Cdim + c] = (f16)v;
}

// ------ both weights: W[K][N] -> W^T fp16 [N][K] (LDS tile transpose) ------
__global__ void convert_both(const float* __restrict__ Wq, f16* __restrict__ WTq,
                             const float* __restrict__ Wp, f16* __restrict__ WTp) {
    __shared__ float tile[32][33];
    int bx = blockIdx.x;
    const float* W; f16* WT; int N, nt;
    if (bx < K3C / 32) { W = Wq; WT = WTq; N = K3C; nt = bx * 32; }
    else               { W = Wp; WT = WTp; N = Cdim; nt = (bx - K3C / 32) * 32; }
    int kt = blockIdx.y * 32;
    int tx = threadIdx.x & 31, ty = threadIdx.x >> 5;
    #pragma unroll
    for (int r = 0; r < 32; r += 8)
        tile[ty + r][tx] = W[(size_t)(kt + ty + r) * N + nt + tx];
    __syncthreads();
    #pragma unroll
    for (int r = 0; r < 32; r += 8) {
        int n = nt + ty + r, k = kt + tx;
        WT[(size_t)n * Kdim + k] = (f16)tile[tx][ty + r];
    }
}

// ==================== MFMA fp16 GEMM (3-buf counted-vmcnt, XCD-part.) ======
// r23: best-measured GEMM (r17: 73.2-73.6us qkv) -- 3-buffer 48KB,
// launch_bounds(256,3), counted vmcnt(4) in main loop (prefetch loads stay
// in flight across barriers), r17-verified conflict-free swizzle pair,
// XCD M-partition, fused output epilogues.
__global__ __launch_bounds__(256, 3)
void mfma_gemm(const f16* __restrict__ A, const f16* __restrict__ W,
               const float* __restrict__ bias, int M, int Nn, int mode, int nNb,
               float* __restrict__ outF, float* __restrict__ sbuf,
               f16* __restrict__ outH) {
    __shared__ __align__(16) f16 smem[3][2][4096];
    const int idx = blockIdx.x;
    const int xcd = idx & 7;
    const int sidx = idx >> 3;
    const int mloc = sidx % 13;
    const int nb = sidx / 13;
    const int cnt = (xcd < 4) ? 13 : 12;
    if (mloc >= cnt) return;
    const int mb = (xcd < 4 ? xcd * 13 : 52 + (xcd - 4) * 12) + mloc;
    const int mBase = mb * 128, nBase = nb * 128;

    const int tid = threadIdx.x;
    const int w = tid >> 6, lane = tid & 63;
    const int lr = lane & 15, lg = lane >> 4;
    const int wr = w >> 1, wc = w & 1;

    const f16* src = (w < 2) ? A : W;
    const int arr = w >> 1;
    const int rowOff = (w & 1) * 64;
    const int rowBase = (w < 2) ? mBase : nBase;
    const int rowMax  = (w < 2) ? (M - 1) : (Nn - 1);
    const int cg = (lane & 3) ^ ((lane >> 3) & 3);   // inverse chunk swizzle
    const int sl8 = (lg ^ ((lr >> 1) & 3)) * 8;      // read-side swizzled slot

    f32x4 acc[4][4];
    #pragma unroll
    for (int mi = 0; mi < 4; ++mi)
        #pragma unroll
        for (int ni = 0; ni < 4; ++ni) {
            acc[mi][ni][0] = 0.f; acc[mi][ni][1] = 0.f;
            acc[mi][ni][2] = 0.f; acc[mi][ni][3] = 0.f;
        }

    auto stage = [&](int buf, int k0) {
        #pragma unroll
        for (int i = 0; i < 4; ++i) {
            int r16 = rowOff + i * 16;
            int grow = min(rowBase + r16 + (lane >> 2), rowMax);
            const f16* g = src + (size_t)grow * Kdim + k0 + cg * 8;
            f16* l = &smem[buf][arr][r16 * 32];
            __builtin_amdgcn_global_load_lds(
                (const __attribute__((address_space(1))) void*)g,
                (__attribute__((address_space(3))) void*)l, 16, 0, 0);
        }
    };

    const int NT = Kdim / 32;  // 24
    stage(0, 0);
    stage(1, 32);
    asm volatile("s_waitcnt vmcnt(4)" ::: "memory");
    __builtin_amdgcn_sched_barrier(0);
    __builtin_amdgcn_s_barrier();
    __builtin_amdgcn_sched_barrier(0);

    int cur = 0;
    for (int t = 0; t < NT; ++t) {
        if (t + 2 < NT) {
            int nbuf = cur + 2; if (nbuf >= 3) nbuf -= 3;
            stage(nbuf, (t + 2) * 32);
        }
        const f16* AS = &smem[cur][0][0];
        const f16* WS = &smem[cur][1][0];
        half8 a[4], b[4];
        #pragma unroll
        for (int mi = 0; mi < 4; ++mi)
            a[mi] = *reinterpret_cast<const half8*>(&AS[(wr * 64 + mi * 16 + lr) * 32 + sl8]);
        #pragma unroll
        for (int ni = 0; ni < 4; ++ni)
            b[ni] = *reinterpret_cast<const half8*>(&WS[(wc * 64 + ni * 16 + lr) * 32 + sl8]);
        #pragma unroll
        for (int mi = 0; mi < 4; ++mi)
            #pragma unroll
            for (int ni = 0; ni < 4; ++ni)
                acc[mi][ni] = __builtin_amdgcn_mfma_f32_16x16x32_f16(a[mi], b[ni], acc[mi][ni], 0, 0, 0);

        if (t + 1 < NT) {
            if (t + 2 < NT)
                asm volatile("s_waitcnt vmcnt(4) lgkmcnt(0)" ::: "memory");
            else
                asm volatile("s_waitcnt vmcnt(0) lgkmcnt(0)" ::: "memory");
            __builtin_amdgcn_sched_barrier(0);
            __builtin_amdgcn_s_barrier();
            __builtin_amdgcn_sched_barrier(0);
        }
        cur = cur + 1; if (cur >= 3) cur -= 3;
    }

    if (mode == 0) {
        #pragma unroll
        for (int ni = 0; ni < 4; ++ni) {
            int gn = nBase + wc * 64 + ni * 16 + lr;
            float bv = bias ? bias[gn] : 0.f;
            #pragma unroll
            for (int mi = 0; mi < 4; ++mi)
                #pragma unroll
                for (int r = 0; r < 4; ++r) {
                    int gm = mBase + wr * 64 + mi * 16 + lg * 4 + r;
                    if (gm < M) {
                        int bb = gm / Ttok, tt = gm - bb * Ttok;
                        float v = acc[mi][ni][r] + bv;
                        if (tt >= 1 && tt < Ntok)
                            outF[((size_t)bb * Ntok + tt) * Nn + gn] = v;
                        else
                            sbuf[((size_t)bb * 13 + (tt == 0 ? 0 : tt - Ntok + 1)) * Nn + gn] = v;
                    }
                }
        }
    } else {
        __syncthreads();
        f16* Ew = &smem[0][0][0] + (size_t)w * 4096;
        #pragma unroll
        for (int mi = 0; mi < 4; ++mi)
            #pragma unroll
            for (int ni = 0; ni < 4; ++ni)
                #pragma unroll
                for (int r = 0; r < 4; ++r) {
                    int er = mi * 16 + lg * 4 + r;
                    int ec = ni * 16 + lr;
                    int chunk = ec >> 3;
                    Ew[er * 64 + ((chunk ^ (er & 7)) << 3) + (ec & 7)] = (f16)acc[mi][ni][r];
                }
        __syncthreads();
        int scol = nBase + wc * 64;
        int s = scol / Cdim;
        int hc = scol - s * Cdim;
        int h = hc >> 6;
        #pragma unroll
        for (int c8 = 0; c8 < 8; ++c8) {
            int er = (lane >> 3) + c8 * 8;
            int chunk = lane & 7;
            half8 v = *reinterpret_cast<const half8*>(&Ew[er * 64 + ((chunk ^ (er & 7)) << 3)]);
            int gm = mBase + wr * 64 + er;
            if (gm < M) {
                int bb = gm / Ttok, tt = gm - bb * Ttok;
                f16* dst = outH + (((size_t)(s * Bsz + bb) * Hn + h) * Ttok + tt) * HD + chunk * 8;
                *reinterpret_cast<half8*>(dst) = v;
            }
        }
    }
}

// ==================== MFMA fp16 flash attention (async dbuf, XCD-pinned) ===
__global__ __launch_bounds__(256, 2)
void flash_attn_kernel(const f16* __restrict__ Qb, const f16* __restrict__ Kb,
                       const f16* __restrict__ Vb, f16* __restrict__ ao) {
    __shared__ __align__(16) unsigned short KS[2][64 * 64];
    __shared__ __align__(16) unsigned short VS[2][64 * 64];

    int bh   = blockIdx.x % (Bsz * Hn);
    int part = blockIdx.x / (Bsz * Hn);
    int st   = 3 * part - (part == 4 ? 1 : 0);   // 0,3,6,9,11
    int q0   = st * 64;
    int smax = (part < 3) ? 3 : 2;
    int tid = threadIdx.x;
    int w = tid >> 6, lane = tid & 63;
    int lr = lane & 15, lg = lane >> 4;
    size_t base = (size_t)bh * Ttok * HD;

    half8 qf[NQS][2];
    #pragma unroll
    for (int s = 0; s < NQS; ++s) {
        int qrow = q0 + s * 64 + w * 16 + lr;
        int crow = min(qrow, Ttok - 1);
        #pragma unroll
        for (int kf = 0; kf < 2; ++kf)
            qf[s][kf] = *reinterpret_cast<const half8*>(Qb + base + (size_t)crow * HD + kf * 32 + lg * 8);
    }

    f32x4 O[NQS][4];
    float lsum[NQS];
    #pragma unroll
    for (int s = 0; s < NQS; ++s) {
        lsum[s] = 0.f;
        #pragma unroll
        for (int nt = 0; nt < 4; ++nt) { O[s][nt][0]=0.f; O[s][nt][1]=0.f; O[s][nt][2]=0.f; O[s][nt][3]=0.f; }
    }

    const unsigned short* Kg = (const unsigned short*)(Kb + base);
    const unsigned short* Vg = (const unsigned short*)(Vb + base);

    int pr = tid >> 3;          // key pair 0..31
    int g  = tid & 7;           // dim group (8 dims)
    int k0 = 2 * pr, k1 = k0 + 1;

    ushort8 kv0, kv1, vv0, vv1;
    auto load_tile = [&](int kt) {
        int gk0 = kt * 64 + k0;
        if (kt < 12) {
            kv0 = *reinterpret_cast<const ushort8*>(&Kg[(size_t)gk0 * HD + g * 8]);
            vv0 = *reinterpret_cast<const ushort8*>(&Vg[(size_t)gk0 * HD + g * 8]);
            kv1 = *reinterpret_cast<const ushort8*>(&Kg[(size_t)(gk0 + 1) * HD + g * 8]);
            vv1 = *reinterpret_cast<const ushort8*>(&Vg[(size_t)(gk0 + 1) * HD + g * 8]);
        } else {
            ushort8 z;
            #pragma unroll
            for (int jj = 0; jj < 8; ++jj) z[jj] = 0;
            kv0 = z; vv0 = z; kv1 = z; vv1 = z;
            if (gk0 < Ttok) {
                kv0 = *reinterpret_cast<const ushort8*>(&Kg[(size_t)gk0 * HD + g * 8]);
                vv0 = *reinterpret_cast<const ushort8*>(&Vg[(size_t)gk0 * HD + g * 8]);
            }
            if (gk0 + 1 < Ttok) {
                kv1 = *reinterpret_cast<const ushort8*>(&Kg[(size_t)(gk0 + 1) * HD + g * 8]);
                vv1 = *reinterpret_cast<const ushort8*>(&Vg[(size_t)(gk0 + 1) * HD + g * 8]);
            }
        }
    };
    auto write_tile = [&](int buf) {
        *reinterpret_cast<ushort8*>(&KS[buf][(k0 * 64 + g * 8) ^ SW(k0)]) = kv0;
        *reinterpret_cast<ushort8*>(&KS[buf][(k1 * 64 + g * 8) ^ SW(k1)]) = kv1;
        unsigned* VTd = reinterpret_cast<unsigned*>(&VS[buf][0]);
        #pragma unroll
        for (int jj = 0; jj < 8; ++jj) {
            int dim = g * 8 + jj;
            unsigned w2 = (unsigned)vv0[jj] | ((unsigned)vv1[jj] << 16);
            VTd[dim * 32 + (pr ^ ((((dim & 7) ^ ((dim >> 3) & 7))) << 2))] = w2;
        }
    };

    load_tile(0);
    write_tile(0);
    load_tile(1);
    asm volatile("s_waitcnt lgkmcnt(0)" ::: "memory");
    __builtin_amdgcn_sched_barrier(0);
    __builtin_amdgcn_s_barrier();
    __builtin_amdgcn_sched_barrier(0);

    for (int kt = 0; kt < 13; ++kt) {
        bool tail = (kt == 12);
        int cur = kt & 1;
        const unsigned short* KSc = &KS[cur][0];
        const unsigned short* VSc = &VS[cur][0];

        int kbase = kt * 64;
        #pragma unroll
        for (int s = 0; s < NQS; ++s) {
            if (s < smax) {
                half4v pa[4];
                float ls = 0.f;
                #pragma unroll
                for (int ntk = 0; ntk < 4; ++ntk) {
                    f32x4 sc; sc[0]=0.f; sc[1]=0.f; sc[2]=0.f; sc[3]=0.f;
                    #pragma unroll
                    for (int kf = 0; kf < 2; ++kf) {
                        int key = ntk * 16 + lr;
                        int d0 = kf * 32 + lg * 8;
                        half8 k8 = *reinterpret_cast<const half8*>(
                            reinterpret_cast<const f16*>(&KSc[(key * 64 + d0) ^ SW(key)]));
                        sc = __builtin_amdgcn_mfma_f32_16x16x32_f16(k8, qf[s][kf], sc, 0, 0, 0);
                    }
                    float p[4];
                    if (!tail) {
                        #pragma unroll
                        for (int r = 0; r < 4; ++r) {
                            p[r] = __expf(sc[r] * 0.125f - 6.0f);
                            ls += p[r];
                        }
                    } else {
                        int kb2 = kbase + ntk * 16 + lg * 4;
                        #pragma unroll
                        for (int r = 0; r < 4; ++r) {
                            bool valid = (kb2 + r) < Ttok;
                            p[r] = valid ? __expf(sc[r] * 0.125f - 6.0f) : 0.f;
                            ls += p[r];
                        }
                    }
                    auto lo = __builtin_amdgcn_cvt_pkrtz(p[0], p[1]);
                    auto hi = __builtin_amdgcn_cvt_pkrtz(p[2], p[3]);
                    pa[ntk][0] = (f16)lo[0]; pa[ntk][1] = (f16)lo[1];
                    pa[ntk][2] = (f16)hi[0]; pa[ntk][3] = (f16)hi[1];
                }
                lsum[s] += ls;
                #pragma unroll
                for (int ntd = 0; ntd < 4; ++ntd) {
                    int dim = ntd * 16 + lr;
                    #pragma unroll
                    for (int ntk = 0; ntk < 4; ++ntk) {
                        half4v v4 = *reinterpret_cast<const half4v*>(
                            reinterpret_cast<const f16*>(&VSc[(dim * 64 + ntk * 16 + lg * 4) ^ SW(dim)]));
                        O[s][ntd] = __builtin_amdgcn_mfma_f32_16x16x16f16(pa[ntk], v4, O[s][ntd], 0, 0, 0);
                    }
                }
            }
        }

        if (kt + 1 < 13) {
            write_tile((kt + 1) & 1);
            if (kt + 2 < 13) load_tile(kt + 2);
            asm volatile("s_waitcnt lgkmcnt(0)" ::: "memory");
            __builtin_amdgcn_sched_barrier(0);
            __builtin_amdgcn_s_barrier();
            __builtin_amdgcn_sched_barrier(0);
        }
    }

    __syncthreads();
    int b = bh / Hn, h = bh % Hn;
    f16* Ew = reinterpret_cast<f16*>(&KS[0][(size_t)w * 1024]);
    #pragma unroll
    for (int s = 0; s < NQS; ++s) {
        if (s < smax) {
            float l = lsum[s];
            l += __shfl_xor(l, 16, 64);
            l += __shfl_xor(l, 32, 64);
            float inv[4];
            #pragma unroll
            for (int r = 0; r < 4; ++r)
                inv[r] = 1.0f / __shfl(l, lg * 4 + r, 64);
            #pragma unroll
            for (int nt = 0; nt < 4; ++nt)
                #pragma unroll
                for (int r = 0; r < 4; ++r)
                    Ew[(lg * 4 + r) * 64 + nt * 16 + lr] = (f16)(O[s][nt][r] * inv[r]);
            int row = lane >> 2, seg = lane & 3;
            half8 v0 = *reinterpret_cast<const half8*>(&Ew[row * 64 + seg * 16]);
            half8 v1 = *reinterpret_cast<const half8*>(&Ew[row * 64 + seg * 16 + 8]);
            int qrow = q0 + s * 64 + w * 16 + row;
            if (qrow < Ttok) {
                f16* dst = ao + ((size_t)b * Ttok + qrow) * Cdim + h * HD + seg * 16;
                *reinterpret_cast<half8*>(dst) = v0;
                *reinterpret_cast<half8*>(dst + 8) = v1;
            }
        }
    }
}

// -------------------- cls row from side buffer -----------------------------
__global__ void cls2_kernel(const float* __restrict__ sbuf, float* __restrict__ out) {
    int b = blockIdx.x, t = threadIdx.x;
    #pragma unroll
    for (int i = 0; i < 3; ++i) {
        int c = t + i * 256;
        float s = sbuf[((size_t)b * 13) * Cdim + c];
        float hs = 0.f;
        #pragma unroll
        for (int h = 0; h < Hn; ++h)
            hs += sbuf[((size_t)b * 13 + 1 + h) * Cdim + c];
        out[((size_t)b * Ntok) * Cdim + c] = s + hs * (1.0f / (float)Hn);
    }
}

extern "C" void kernel_launch(void* const* d_in, const int* in_sizes, int n_in,
                              void* d_out, int out_size, void* d_ws, size_t ws_size,
                              hipStream_t stream) {
    const float* x      = (const float*)d_in[0];
    const float* qkv_w  = (const float*)d_in[1];
    const float* proj_w = (const float*)d_in[2];
    const float* proj_b = (const float*)d_in[3];
    const float* htp_w  = (const float*)d_in[4];
    const float* htp_b  = (const float*)d_in[5];
    const float* ln_g   = (const float*)d_in[6];
    const float* ln_b   = (const float*)d_in[7];
    const float* pos    = (const float*)d_in[8];
    float* out = (float*)d_out;

    const size_t MC = (size_t)Mrows * Cdim;        // 9,793,536
    const size_t WQ = (size_t)K3C * Kdim;          // 1,769,472
    const size_t WP = (size_t)Cdim * Kdim;         // 589,824

    f16* qkv   = (f16*)d_ws;                       // 3*MC f16 (Q,K,V)
    f16* xa    = qkv + 3 * MC;                     // MC f16 (input; later attnout)
    f16* wq    = xa + MC;                          // WQ f16  (qkv_w^T)
    f16* wp    = wq + WQ;                          // WP f16  (proj_w^T)
    float* partial = (float*)(wp + WP);            // B*16*C fp32
    float* sbuf    = partial + (size_t)Bsz * 16 * Cdim;  // B*13*C fp32

    prep_x<<<dim3(Bsz, 16), 256, 0, stream>>>(x, xa, partial);
    headtok_kernel<<<Bsz * Hn * Hn, 64, 0, stream>>>(partial, htp_w, htp_b, ln_g, ln_b, pos, xa);
    convert_both<<<dim3(96, Kdim / 32), 256, 0, stream>>>(qkv_w, wq, proj_w, wp);

    mfma_gemm<<<8 * 13 * 18, 256, 0, stream>>>(
        xa, wq, nullptr, Mrows, K3C, 1, 18, nullptr, nullptr, qkv);

    flash_attn_kernel<<<Bsz * Hn * NPARTS, 256, 0, stream>>>(
        qkv, qkv + MC, qkv + 2 * MC, xa);

    mfma_gemm<<<8 * 13 * 6, 256, 0, stream>>>(
        xa, wp, proj_b, Mrows, Cdim, 0, 6, out, sbuf, nullptr);

    cls2_kernel<<<Bsz, 256, 0, stream>>>(sbuf, out);
}